// Round 8
// baseline (228.208 us; speedup 1.0000x reference)
//
#include <hip/hip_runtime.h>

// InputDefenseLayer: clip(x, -3.5, 3.5) then EMA scan along T (axis 1):
//   s_0 = xc_0 ; s_t = 0.25*xc_t + 0.75*s_{t-1}
// x: (B=64, T=2048, C=256) float32, contiguous, C innermost.
//
// R9: ONE variable vs R7 -- prefetch depth PF 8 -> 16 (two banks p/q).
//  - R8 was the discriminating test: waves alone (4096 @ 512 B) did NOT
//    recover R6's rate; outstanding-bytes did line up across R6/R7/R8:
//    32 MB -> 4.4-4.7 TB/s, 16 MB -> 4.0-4.3 TB/s. Little's law, nt loads
//    ride HBM-direct with multi-us loaded latency; 32 MB still unsaturated.
//  - R9 restores 32 MB outstanding (2048 waves x 16 x 1 KiB) at L=64's
//    1.36x traffic (303 MB total) -- first round combining low traffic
//    WITH high outstanding.
//  - Two named register banks (p0..p7, q0..q7), groups of 8 rows, reload
//    distance 16: group g consumes bank g%2 and reissues it for rows
//    r0+16..r0+23. All indices compile-time (no runtime-indexed arrays).
//  - nt loads + nt stores kept (R6's L3-dirty-eviction fix: never allocate,
//    never evict the reset-fill's dirty lines in-window).
// Numerics: same W=24 seed, same fmaf order -> absmax 0.0078125 unchanged.

constexpr int B = 64;
constexpr int T = 2048;
constexpr int C = 256;
constexpr int L = 64;            // output chunk length along T
constexpr int W = 24;            // warm-up steps: 7*0.75^24 ~ 7e-3 < 7e-2
constexpr int NCHUNK = T / L;    // 32
constexpr int ROWF4 = C / 4;     // 64 float4 per t-row
constexpr int PFD = 16;          // prefetch distance (two 8-row banks)

#define CLIP_LO -3.5f
#define CLIP_HI  3.5f
#define EMA_A 0.25f
#define EMA_B 0.75f

typedef float f4 __attribute__((ext_vector_type(4)));

__device__ __forceinline__ float clipf(float v) {
    return fminf(fmaxf(v, CLIP_LO), CLIP_HI);   // -> v_med3_f32
}

__device__ __forceinline__ f4 clip4(f4 v) {
    f4 r;
    r.x = clipf(v.x);
    r.y = clipf(v.y);
    r.z = clipf(v.z);
    r.w = clipf(v.w);
    return r;
}

__device__ __forceinline__ f4 ema4(f4 s, f4 v) {
    f4 r;
    r.x = fmaf(EMA_A, v.x, EMA_B * s.x);
    r.y = fmaf(EMA_A, v.y, EMA_B * s.y);
    r.z = fmaf(EMA_A, v.z, EMA_B * s.z);
    r.w = fmaf(EMA_A, v.w, EMA_B * s.w);
    return r;
}

// Non-temporal (non-allocating) 16-B load/store.
#define NTLOAD(p)     __builtin_nontemporal_load(p)
#define NTSTORE(v, p) __builtin_nontemporal_store((v), (p))

// Consume row r from named bank register P; re-issue load for row r+PFD
// into the same register. Guards fold at compile time (r, N constants).
#define STEPB(P, r)                                                  \
    {                                                                \
        f4 v = clip4(P);                                             \
        s = ((r) == 0) ? v : ema4(s, v);                             \
        if ((r) + PFD < N) P = NTLOAD(&xp[((r) + PFD) * ROWF4]);     \
    }

// Same, but also latch the state into output register oo (named, static).
#define OSTEPB(P, r, oo)                                             \
    {                                                                \
        f4 v = clip4(P);                                             \
        s = ((r) == 0) ? v : ema4(s, v);                             \
        oo = s;                                                      \
        if ((r) + PFD < N) P = NTLOAD(&xp[((r) + PFD) * ROWF4]);     \
    }

// 8 warm-up rows starting at row r0, consuming bank B0..B7.
#define G8W(B, r0)                                                   \
    STEPB(B##0, (r0) + 0) STEPB(B##1, (r0) + 1)                      \
    STEPB(B##2, (r0) + 2) STEPB(B##3, (r0) + 3)                      \
    STEPB(B##4, (r0) + 4) STEPB(B##5, (r0) + 5)                      \
    STEPB(B##6, (r0) + 6) STEPB(B##7, (r0) + 7)

// 8 output rows starting at r0 from bank B (loads-only vmcnt stream),
// then a pinned back-to-back nt store burst of o0..o7.
#define G8S(B, r0)                                                   \
    OSTEPB(B##0, (r0) + 0, o0) OSTEPB(B##1, (r0) + 1, o1)            \
    OSTEPB(B##2, (r0) + 2, o2) OSTEPB(B##3, (r0) + 3, o3)            \
    OSTEPB(B##4, (r0) + 4, o4) OSTEPB(B##5, (r0) + 5, o5)            \
    OSTEPB(B##6, (r0) + 6, o6) OSTEPB(B##7, (r0) + 7, o7)            \
    __builtin_amdgcn_sched_barrier(0);                               \
    NTSTORE(o0, op + ((r0) + 0) * ROWF4);                            \
    NTSTORE(o1, op + ((r0) + 1) * ROWF4);                            \
    NTSTORE(o2, op + ((r0) + 2) * ROWF4);                            \
    NTSTORE(o3, op + ((r0) + 3) * ROWF4);                            \
    NTSTORE(o4, op + ((r0) + 4) * ROWF4);                            \
    NTSTORE(o5, op + ((r0) + 5) * ROWF4);                            \
    NTSTORE(o6, op + ((r0) + 6) * ROWF4);                            \
    NTSTORE(o7, op + ((r0) + 7) * ROWF4);                            \
    __builtin_amdgcn_sched_barrier(0);

// Process rows [0, N): row 0 seeds the EMA state, rows >= SKIP are stored.
// Group g (rows 8g..8g+7) consumes bank g%2 (p for even, q for odd);
// prologue fills p with rows 0-7 and q with rows 8-15.
template <int N, int SKIP>
__device__ __forceinline__ void run_rows(const f4* __restrict__ xp,
                                         f4* __restrict__ op) {
    f4 p0 = NTLOAD(&xp[0 * ROWF4]);
    f4 p1 = NTLOAD(&xp[1 * ROWF4]);
    f4 p2 = NTLOAD(&xp[2 * ROWF4]);
    f4 p3 = NTLOAD(&xp[3 * ROWF4]);
    f4 p4 = NTLOAD(&xp[4 * ROWF4]);
    f4 p5 = NTLOAD(&xp[5 * ROWF4]);
    f4 p6 = NTLOAD(&xp[6 * ROWF4]);
    f4 p7 = NTLOAD(&xp[7 * ROWF4]);
    f4 q0 = NTLOAD(&xp[8 * ROWF4]);
    f4 q1 = NTLOAD(&xp[9 * ROWF4]);
    f4 q2 = NTLOAD(&xp[10 * ROWF4]);
    f4 q3 = NTLOAD(&xp[11 * ROWF4]);
    f4 q4 = NTLOAD(&xp[12 * ROWF4]);
    f4 q5 = NTLOAD(&xp[13 * ROWF4]);
    f4 q6 = NTLOAD(&xp[14 * ROWF4]);
    f4 q7 = NTLOAD(&xp[15 * ROWF4]);
    f4 s = {};
    f4 o0, o1, o2, o3, o4, o5, o6, o7;

    if constexpr (SKIP == 0) {
        static_assert(N == L, "k==0 path is 64 rows");
        G8S(p, 0)
        G8S(q, 8)
        G8S(p, 16)
        G8S(q, 24)
        G8S(p, 32)
        G8S(q, 40)
        G8S(p, 48)
        G8S(q, 56)
    } else {
        static_assert(SKIP == W && N == W + L, "warm-up path is 24+64 rows");
        G8W(p, 0)
        G8W(q, 8)
        G8W(p, 16)
        G8S(q, 24)
        G8S(p, 32)
        G8S(q, 40)
        G8S(p, 48)
        G8S(q, 56)
        G8S(p, 64)
        G8S(q, 72)
        G8S(p, 80)
    }
}

__global__ __launch_bounds__(256, 2) void ema_kernel(
    const float* __restrict__ x, float* __restrict__ out)
{
    // 4 chunk-jobs per 256-thread block; 64 float4-lanes (1 wave) each.
    const int job  = blockIdx.x * 4 + (threadIdx.x >> 6);
    const int lane = threadIdx.x & 63;
    const int b    = job >> 5;            // / NCHUNK (32)
    const int k    = job & (NCHUNK - 1);  // % NCHUNK
    const int t0   = k * L;
    const int tb   = (k == 0) ? 0 : (t0 - W);

    const f4* __restrict__ xp = (const f4*)x + ((size_t)b * T + tb) * ROWF4 + lane;
    f4* __restrict__ op       = (f4*)out     + ((size_t)b * T + tb) * ROWF4 + lane;

    if (k == 0) {
        run_rows<L, 0>(xp, op);           // exact from t=0, store all 64 rows
    } else {
        run_rows<W + L, W>(xp, op);       // 24 warm-up rows, store last 64
    }
}

extern "C" void kernel_launch(void* const* d_in, const int* in_sizes, int n_in,
                              void* d_out, int out_size, void* d_ws, size_t ws_size,
                              hipStream_t stream) {
    const float* x = (const float*)d_in[0];
    float* out = (float*)d_out;
    const int n_jobs = B * NCHUNK;                 // 2048
    ema_kernel<<<dim3(n_jobs / 4), dim3(256), 0, stream>>>(x, out);
}